// Round 11
// baseline (86.903 us; speedup 1.0000x reference)
//
#include <hip/hip_runtime.h>
#include <hip/hip_bf16.h>

typedef __attribute__((ext_vector_type(8))) short short8;
typedef __attribute__((ext_vector_type(4))) float floatx4;

#define L2EPS 1e-12f

__device__ __forceinline__ unsigned short f2bf(float f) {
  union { float f; unsigned u; } c; c.f = f;
  unsigned u = c.u;
  unsigned r = (u + 0x7fffu + ((u >> 16) & 1u)) >> 16;  // RNE
  return (unsigned short)r;
}

__device__ __forceinline__ void gload_lds16(const void* g, void* l) {
  __builtin_amdgcn_global_load_lds(
      (const __attribute__((address_space(1))) unsigned int*)g,
      (__attribute__((address_space(3))) unsigned int*)l,
      16, 0, 0);
}

// ---------------------------------------------------------------------------
// Kernel 1: per-row inverse L2 norm of W (D rows of length N). One block/row.
// ---------------------------------------------------------------------------
__global__ __launch_bounds__(256) void wnorm_kernel(const float* __restrict__ W,
                                                    float* __restrict__ rnw, int N) {
  const int d = blockIdx.x;
  const float2* row2 = (const float2*)(W + (size_t)d * N);
  const int n2 = N >> 1;
  float s = 0.f;
  for (int i = threadIdx.x; i < n2; i += 256) {
    const float2 v = row2[i];
    s += v.x * v.x + v.y * v.y;
  }
  if (threadIdx.x == 0 && (N & 1)) {
    const float v = W[(size_t)d * N + (N - 1)];
    s += v * v;
  }
#pragma unroll
  for (int off = 32; off > 0; off >>= 1) s += __shfl_xor(s, off);
  __shared__ float red[4];
  if ((threadIdx.x & 63) == 0) red[threadIdx.x >> 6] = s;
  __syncthreads();
  if (threadIdx.x == 0) {
    const float t = red[0] + red[1] + red[2] + red[3];
    rnw[d] = rsqrtf(fmaxf(t, L2EPS));
  }
}

// ---------------------------------------------------------------------------
// Kernel 2 (fused dispatch): blocks [0,nxb): normalize x rows AND fold rnw.
// Blocks [nxb,...): transpose-cast BT[n][d] = bf16(W[d][n]), zero-padded.
// ---------------------------------------------------------------------------
__global__ __launch_bounds__(256) void prep_kernel(const float* __restrict__ x,
                                                   const float* __restrict__ W,
                                                   const float* __restrict__ rnw,
                                                   unsigned short* __restrict__ xb,
                                                   unsigned short* __restrict__ BT,
                                                   int N, int nxb, int nwx) {
  const int bid = blockIdx.x;
  if (bid < nxb) {
    const int lane = threadIdx.x & 63;
    const int wave = threadIdx.x >> 6;
    const int row  = bid * 4 + wave;
    const float4* xr = (const float4*)(x + (size_t)row * 512);
    const float4 v0 = xr[lane * 2];
    const float4 v1 = xr[lane * 2 + 1];
    float s = v0.x*v0.x + v0.y*v0.y + v0.z*v0.z + v0.w*v0.w
            + v1.x*v1.x + v1.y*v1.y + v1.z*v1.z + v1.w*v1.w;
#pragma unroll
    for (int off = 32; off > 0; off >>= 1) s += __shfl_xor(s, off);
    const float r = rsqrtf(fmaxf(s, L2EPS));
    const float4 w0 = ((const float4*)rnw)[lane * 2];
    const float4 w1 = ((const float4*)rnw)[lane * 2 + 1];
    short8 o;
    o[0] = (short)f2bf(v0.x * r * w0.x); o[1] = (short)f2bf(v0.y * r * w0.y);
    o[2] = (short)f2bf(v0.z * r * w0.z); o[3] = (short)f2bf(v0.w * r * w0.w);
    o[4] = (short)f2bf(v1.x * r * w1.x); o[5] = (short)f2bf(v1.y * r * w1.y);
    o[6] = (short)f2bf(v1.z * r * w1.z); o[7] = (short)f2bf(v1.w * r * w1.w);
    *(short8*)(xb + (size_t)row * 512 + lane * 8) = o;
  } else {
    __shared__ unsigned short tile[32][33];
    const int wb = bid - nxb;
    const int n0 = (wb % nwx) * 32;
    const int d0 = (wb / nwx) * 32;
    const int tx = threadIdx.x & 31;
    const int ty = threadIdx.x >> 5;  // 0..7
#pragma unroll
    for (int i = 0; i < 4; ++i) {
      const int dl = ty + i * 8;
      const int n = n0 + tx;
      float v = 0.f;
      if (n < N) v = W[(size_t)(d0 + dl) * N + n];
      tile[tx][dl] = f2bf(v);
    }
    __syncthreads();
#pragma unroll
    for (int i = 0; i < 4; ++i) {
      const int nl = ty + i * 8;
      BT[(size_t)(n0 + nl) * 512 + d0 + tx] = tile[nl][tx];
    }
  }
}

// ---------------------------------------------------------------------------
// Kernel 3: GEMM = r8 skeleton EXACTLY (128x128, 4 waves, BK=64, single LDS
// buffer, compiler-owned schedule, chunk-XOR swizzle both sides, XCD column
// chunks) + ONE change: NON-TEMPORAL C stores, so the 98MB output stream
// does not evict the L2-resident A (4MB) / B-panel working set.
// ---------------------------------------------------------------------------
__global__ __launch_bounds__(256, 4) void gemm_kernel(
    const unsigned short* __restrict__ A,   // (4096,512) bf16 (xn * rnw)
    const unsigned short* __restrict__ BT,  // (6016,512) bf16 (W^T)
    float* __restrict__ C,                  // (4096,N) f32
    int N, int nbx, int nby) {
  __shared__ unsigned short As[128 * 64];
  __shared__ unsigned short Bs[128 * 64];

  const int tid = threadIdx.x;
  const int l   = tid & 63;
  const int w   = tid >> 6;   // 0..3
  const int wr  = w >> 1;     // 0..1
  const int wc  = w & 1;      // 0..1

  // XCD swizzle: 1504 = 8 x 188; column-major chunks (B-panel L2 reuse).
  const int grid = nbx * nby;
  const int bid  = blockIdx.x;
  int swz = bid;
  if ((grid & 7) == 0) swz = (bid & 7) * (grid >> 3) + (bid >> 3);
  const int bx = swz / nby;
  const int by = swz % nby;
  const int row0 = by * 128;
  const int col0 = bx * 128;

  floatx4 acc[4][4];
#pragma unroll
  for (int m = 0; m < 4; ++m)
#pragma unroll
    for (int n = 0; n < 4; ++n)
      acc[m][n] = (floatx4){0.f, 0.f, 0.f, 0.f};

  // staging: one instr = 256 thr x 16B = 4KB = 32 rows of 128B; 4 per matrix.
  // LDS dest linear (tid*16B); SOURCE chunk pre-swizzled (rule #21):
  // chunk_g = (tid&7) ^ (row&7), row&7 = (tid>>3)&7 (rows step by 32).
  const int srow = tid >> 3;                               // 0..31
  const int sch  = ((tid & 7) ^ (srow & 7)) * 8;           // elems
  const unsigned short* Ap = A  + (size_t)(row0 + srow) * 512 + sch;
  const unsigned short* Bp = BT + (size_t)(col0 + srow) * 512 + sch;
  const int lo = tid * 8;                                  // LDS elems

  // frag-read geometry: elem = row*64 + ((ks*4+q4)^(row&7))*8; consecutive
  // 8-lane groups cover 8 distinct 16B bank-groups (0 conflicts, r3-measured).
  const int ln15 = l & 15;
  const int q4   = l >> 4;
  const int e7   = ln15 & 7;
  const int cs0  = ((q4) ^ e7) * 8;
  const int cs1  = ((4 + q4) ^ e7) * 8;
  const int aoff = (wr * 64 + ln15) * 64;   // + m*1024
  const int boff = (wc * 64 + ln15) * 64;   // + n*1024

  for (int t = 0; t < 8; ++t) {
#pragma unroll
    for (int i = 0; i < 4; ++i)
      gload_lds16(Ap + (size_t)(i * 32) * 512 + t * 64, &As[i * 2048 + lo]);
#pragma unroll
    for (int i = 0; i < 4; ++i)
      gload_lds16(Bp + (size_t)(i * 32) * 512 + t * 64, &Bs[i * 2048 + lo]);
    __syncthreads();
#pragma unroll
    for (int ks = 0; ks < 2; ++ks) {
      const int cs = ks ? cs1 : cs0;
      short8 af[4], bf[4];
#pragma unroll
      for (int m = 0; m < 4; ++m) af[m] = *(const short8*)&As[aoff + m * 1024 + cs];
#pragma unroll
      for (int n = 0; n < 4; ++n) bf[n] = *(const short8*)&Bs[boff + n * 1024 + cs];
#pragma unroll
      for (int m = 0; m < 4; ++m)
#pragma unroll
        for (int n = 0; n < 4; ++n)
          acc[m][n] = __builtin_amdgcn_mfma_f32_16x16x32_bf16(af[m], bf[n], acc[m][n], 0, 0, 0);
    }
    __syncthreads();
  }

  // epilogue: C/D layout col=lane&15, row=(lane>>4)*4+r; n-inner; NT stores
  // (nt flag -> bypass L2 pollution; output is write-once, never re-read).
  const int rb = row0 + wr * 64 + q4 * 4;
  const int cb = col0 + wc * 64 + ln15;
#pragma unroll
  for (int m = 0; m < 4; ++m) {
#pragma unroll
    for (int r = 0; r < 4; ++r) {
      const size_t o = (size_t)(rb + m * 16 + r) * N + cb;
#pragma unroll
      for (int n = 0; n < 4; ++n) {
        if (cb + n * 16 < N)
          __builtin_nontemporal_store(acc[m][n][r], &C[o + n * 16]);
      }
    }
  }
}

// ---------------------------------------------------------------------------
extern "C" void kernel_launch(void* const* d_in, const int* in_sizes, int n_in,
                              void* d_out, int out_size, void* d_ws, size_t ws_size,
                              hipStream_t stream) {
  const float* x = (const float*)d_in[0];
  const float* W = (const float*)d_in[1];
  float* out = (float*)d_out;

  const int D = 512;
  const int B = in_sizes[0] / D;            // 4096
  const int N = in_sizes[1] / D;            // 5994
  const int Npad = ((N + 127) / 128) * 128; // 6016

  char* ws = (char*)d_ws;
  unsigned short* xb  = (unsigned short*)ws;                          // B*D*2
  unsigned short* BTb = (unsigned short*)(ws + (size_t)B * D * 2);    // Npad*D*2
  float* rnw = (float*)(ws + (size_t)B * D * 2 + (size_t)Npad * D * 2);

  const int nby = B / 128;         // 32
  const int nbx = Npad / 128;      // 47
  const int nxb = B / 4;           // 1024 xnorm blocks
  const int nwx = Npad / 32;       // 188 wtrans tiles per d-stripe
  const int nwb = nwx * (D / 32);  // 3008 wtrans blocks

  wnorm_kernel<<<D, 256, 0, stream>>>(W, rnw, N);
  prep_kernel<<<nxb + nwb, 256, 0, stream>>>(x, W, rnw, xb, BTb, N, nxb, nwx);
  gemm_kernel<<<nbx * nby, 256, 0, stream>>>(xb, BTb, out, N, nbx, nby);
}

// Round 12
// 75.691 us; speedup vs baseline: 1.1481x; 1.1481x over previous
//
#include <hip/hip_runtime.h>
#include <hip/hip_bf16.h>

typedef __attribute__((ext_vector_type(8))) short short8;
typedef __attribute__((ext_vector_type(4))) float floatx4;

#define L2EPS 1e-12f

__device__ __forceinline__ unsigned short f2bf(float f) {
  union { float f; unsigned u; } c; c.f = f;
  unsigned u = c.u;
  unsigned r = (u + 0x7fffu + ((u >> 16) & 1u)) >> 16;  // RNE
  return (unsigned short)r;
}

__device__ __forceinline__ void gload_lds16(const void* g, void* l) {
  __builtin_amdgcn_global_load_lds(
      (const __attribute__((address_space(1))) unsigned int*)g,
      (__attribute__((address_space(3))) unsigned int*)l,
      16, 0, 0);
}

// ---------------------------------------------------------------------------
// Kernel 1: per-row inverse L2 norm of W (D rows of length N). One block/row.
// ---------------------------------------------------------------------------
__global__ __launch_bounds__(256) void wnorm_kernel(const float* __restrict__ W,
                                                    float* __restrict__ rnw, int N) {
  const int d = blockIdx.x;
  const float2* row2 = (const float2*)(W + (size_t)d * N);
  const int n2 = N >> 1;
  float s = 0.f;
  for (int i = threadIdx.x; i < n2; i += 256) {
    const float2 v = row2[i];
    s += v.x * v.x + v.y * v.y;
  }
  if (threadIdx.x == 0 && (N & 1)) {
    const float v = W[(size_t)d * N + (N - 1)];
    s += v * v;
  }
#pragma unroll
  for (int off = 32; off > 0; off >>= 1) s += __shfl_xor(s, off);
  __shared__ float red[4];
  if ((threadIdx.x & 63) == 0) red[threadIdx.x >> 6] = s;
  __syncthreads();
  if (threadIdx.x == 0) {
    const float t = red[0] + red[1] + red[2] + red[3];
    rnw[d] = rsqrtf(fmaxf(t, L2EPS));
  }
}

// ---------------------------------------------------------------------------
// Kernel 2 (fused dispatch): blocks [0,nxb): normalize x rows AND fold rnw.
// Blocks [nxb,...): transpose-cast BT[n][d] = bf16(W[d][n]), zero-padded.
// ---------------------------------------------------------------------------
__global__ __launch_bounds__(256) void prep_kernel(const float* __restrict__ x,
                                                   const float* __restrict__ W,
                                                   const float* __restrict__ rnw,
                                                   unsigned short* __restrict__ xb,
                                                   unsigned short* __restrict__ BT,
                                                   int N, int nxb, int nwx) {
  const int bid = blockIdx.x;
  if (bid < nxb) {
    const int lane = threadIdx.x & 63;
    const int wave = threadIdx.x >> 6;
    const int row  = bid * 4 + wave;
    const float4* xr = (const float4*)(x + (size_t)row * 512);
    const float4 v0 = xr[lane * 2];
    const float4 v1 = xr[lane * 2 + 1];
    float s = v0.x*v0.x + v0.y*v0.y + v0.z*v0.z + v0.w*v0.w
            + v1.x*v1.x + v1.y*v1.y + v1.z*v1.z + v1.w*v1.w;
#pragma unroll
    for (int off = 32; off > 0; off >>= 1) s += __shfl_xor(s, off);
    const float r = rsqrtf(fmaxf(s, L2EPS));
    const float4 w0 = ((const float4*)rnw)[lane * 2];
    const float4 w1 = ((const float4*)rnw)[lane * 2 + 1];
    short8 o;
    o[0] = (short)f2bf(v0.x * r * w0.x); o[1] = (short)f2bf(v0.y * r * w0.y);
    o[2] = (short)f2bf(v0.z * r * w0.z); o[3] = (short)f2bf(v0.w * r * w0.w);
    o[4] = (short)f2bf(v1.x * r * w1.x); o[5] = (short)f2bf(v1.y * r * w1.y);
    o[6] = (short)f2bf(v1.z * r * w1.z); o[7] = (short)f2bf(v1.w * r * w1.w);
    *(short8*)(xb + (size_t)row * 512 + lane * 8) = o;
  } else {
    __shared__ unsigned short tile[32][33];
    const int wb = bid - nxb;
    const int n0 = (wb % nwx) * 32;
    const int d0 = (wb / nwx) * 32;
    const int tx = threadIdx.x & 31;
    const int ty = threadIdx.x >> 5;  // 0..7
#pragma unroll
    for (int i = 0; i < 4; ++i) {
      const int dl = ty + i * 8;
      const int n = n0 + tx;
      float v = 0.f;
      if (n < N) v = W[(size_t)(d0 + dl) * N + n];
      tile[tx][dl] = f2bf(v);
    }
    __syncthreads();
#pragma unroll
    for (int i = 0; i < 4; ++i) {
      const int nl = ty + i * 8;
      BT[(size_t)(n0 + nl) * 512 + d0 + tx] = tile[nl][tx];
    }
  }
}

// ---------------------------------------------------------------------------
// Kernel 3: BARRIER-FREE wave-private GEMM. 128x128 block tile, 4 waves
// (2x2), each wave owns a 64x64 output tile and a PRIVATE 8KB LDS region
// (A 64x32 + B 64x32 bf16). Zero __syncthreads. Per BK=32 subtile (16
// total): 8 gload_lds -> per-wave vmcnt(0) -> 8 ds_read_b128 -> 16 MFMA.
// lgkmcnt(0) before re-staging guards ds_read-vs-DMA-write on the single
// buffer. Latency hiding = pure wave TLP (16 indep pipelines/CU at 4
// blocks/CU). Chunk-XOR swizzle both sides (r3-measured 0 conflicts).
// Cost: 2x staging duplication, expected L1-absorbed (16KB/CU working set).
// ---------------------------------------------------------------------------
__global__ __launch_bounds__(256, 4) void gemm_kernel(
    const unsigned short* __restrict__ A,   // (4096,512) bf16 (xn * rnw)
    const unsigned short* __restrict__ BT,  // (6016,512) bf16 (W^T)
    float* __restrict__ C,                  // (4096,N) f32
    int N, int nbx, int nby) {
  __shared__ unsigned short lds[4 * 4096];  // [wave][A:2048 | B:2048]

  const int tid = threadIdx.x;
  const int l   = tid & 63;
  const int w   = tid >> 6;   // 0..3
  const int wr  = w >> 1;     // 0..1
  const int wc  = w & 1;      // 0..1

  // XCD swizzle: 1504 = 8 x 188; column-major chunks (B-panel L2 reuse).
  const int grid = nbx * nby;
  const int bid  = blockIdx.x;
  int swz = bid;
  if ((grid & 7) == 0) swz = (bid & 7) * (grid >> 3) + (bid >> 3);
  const int bx = swz / nby;
  const int by = swz % nby;
  const int row0 = by * 128;
  const int col0 = bx * 128;

  floatx4 acc[4][4];
#pragma unroll
  for (int m = 0; m < 4; ++m)
#pragma unroll
    for (int n = 0; n < 4; ++n)
      acc[m][n] = (floatx4){0.f, 0.f, 0.f, 0.f};

  // wave-private staging: one instr = 64 lanes x 16B = 1KB = 16 rows of 64B.
  // srow = l>>2, chunk = l&3; SOURCE chunk pre-swizzled (rule #21):
  // chunk_g = (l&3) ^ ((row>>1)&3), (row>>1)&3 = (l>>3)&3.
  const int srow  = l >> 2;                       // 0..15
  const int chkg  = ((l & 3) ^ ((l >> 3) & 3)) * 8;  // elems
  const unsigned short* Ap = A  + (size_t)(row0 + wr * 64 + srow) * 512 + chkg;
  const unsigned short* Bp = BT + (size_t)(col0 + wc * 64 + srow) * 512 + chkg;
  const int aL = w * 4096 + l * 8;                // + i*512
  const int bL = w * 4096 + 2048 + l * 8;

  // frag-read geometry: row = m*16+ln15 (64B rows), phys chunk = q4^((row>>1)&3)
  // -> 8-lane groups hit 8 distinct 16B slots (r3-measured 0 conflicts).
  const int ln15 = l & 15;
  const int q4   = l >> 4;
  const int cs   = (q4 ^ ((ln15 >> 1) & 3)) * 8;
  const int aR   = w * 4096 + ln15 * 32 + cs;        // + m*512
  const int bR   = w * 4096 + 2048 + ln15 * 32 + cs; // + n*512

#pragma unroll
  for (int t = 0; t < 16; ++t) {
    if (t > 0)  // all ds_reads of tile t-1 retired -> safe to DMA-overwrite
      asm volatile("s_waitcnt lgkmcnt(0)" ::: "memory");
#pragma unroll
    for (int i = 0; i < 4; ++i)
      gload_lds16(Ap + (size_t)(i * 16) * 512 + t * 32, &lds[aL + i * 512]);
#pragma unroll
    for (int i = 0; i < 4; ++i)
      gload_lds16(Bp + (size_t)(i * 16) * 512 + t * 32, &lds[bL + i * 512]);
    asm volatile("s_waitcnt vmcnt(0)" ::: "memory");  // per-wave: DMA landed
    short8 af[4], bf[4];
#pragma unroll
    for (int m = 0; m < 4; ++m) af[m] = *(const short8*)&lds[aR + m * 512];
#pragma unroll
    for (int n = 0; n < 4; ++n) bf[n] = *(const short8*)&lds[bR + n * 512];
#pragma unroll
    for (int m = 0; m < 4; ++m)
#pragma unroll
      for (int n = 0; n < 4; ++n)
        acc[m][n] = __builtin_amdgcn_mfma_f32_16x16x32_bf16(af[m], bf[n], acc[m][n], 0, 0, 0);
  }

  // epilogue: C/D layout col=lane&15, row=(lane>>4)*4+r; n-inner; plain
  // stores through L2 (write-combining; measured near-ideal 103MB).
  const int rb = row0 + wr * 64 + q4 * 4;
  const int cb = col0 + wc * 64 + ln15;
#pragma unroll
  for (int m = 0; m < 4; ++m) {
#pragma unroll
    for (int r = 0; r < 4; ++r) {
      const size_t o = (size_t)(rb + m * 16 + r) * N + cb;
#pragma unroll
      for (int n = 0; n < 4; ++n) {
        if (cb + n * 16 < N) C[o + n * 16] = acc[m][n][r];
      }
    }
  }
}

// ---------------------------------------------------------------------------
extern "C" void kernel_launch(void* const* d_in, const int* in_sizes, int n_in,
                              void* d_out, int out_size, void* d_ws, size_t ws_size,
                              hipStream_t stream) {
  const float* x = (const float*)d_in[0];
  const float* W = (const float*)d_in[1];
  float* out = (float*)d_out;

  const int D = 512;
  const int B = in_sizes[0] / D;            // 4096
  const int N = in_sizes[1] / D;            // 5994
  const int Npad = ((N + 127) / 128) * 128; // 6016

  char* ws = (char*)d_ws;
  unsigned short* xb  = (unsigned short*)ws;                          // B*D*2
  unsigned short* BTb = (unsigned short*)(ws + (size_t)B * D * 2);    // Npad*D*2
  float* rnw = (float*)(ws + (size_t)B * D * 2 + (size_t)Npad * D * 2);

  const int nby = B / 128;         // 32
  const int nbx = Npad / 128;      // 47
  const int nxb = B / 4;           // 1024 xnorm blocks
  const int nwx = Npad / 32;       // 188 wtrans tiles per d-stripe
  const int nwb = nwx * (D / 32);  // 3008 wtrans blocks

  wnorm_kernel<<<D, 256, 0, stream>>>(W, rnw, N);
  prep_kernel<<<nxb + nwb, 256, 0, stream>>>(x, W, rnw, xb, BTb, N, nxb, nwx);
  gemm_kernel<<<nbx * nby, 256, 0, stream>>>(xb, BTb, out, N, nbx, nby);
}

// Round 13
// 63.191 us; speedup vs baseline: 1.3752x; 1.1978x over previous
//
#include <hip/hip_runtime.h>
#include <hip/hip_bf16.h>

typedef __attribute__((ext_vector_type(8))) short short8;
typedef __attribute__((ext_vector_type(4))) float floatx4;

#define L2EPS 1e-12f

__device__ __forceinline__ unsigned short f2bf(float f) {
  union { float f; unsigned u; } c; c.f = f;
  unsigned u = c.u;
  unsigned r = (u + 0x7fffu + ((u >> 16) & 1u)) >> 16;  // RNE
  return (unsigned short)r;
}

__device__ __forceinline__ void gload_lds16(const void* g, void* l) {
  __builtin_amdgcn_global_load_lds(
      (const __attribute__((address_space(1))) unsigned int*)g,
      (__attribute__((address_space(3))) unsigned int*)l,
      16, 0, 0);
}

// ---------------------------------------------------------------------------
// Kernel 1 (fused, independent halves):
//   blocks [0, nxb):        xnorm: xb[row] = bf16(x[row] * rsqrt(sum x^2))
//   blocks [nxb, nxb+D):    wnorm: rnw[d] = rsqrt(max(sum_n W[d,n]^2, eps))
// (rnw is folded into BT in kernel 2, so xnorm does NOT depend on wnorm.)
// ---------------------------------------------------------------------------
__global__ __launch_bounds__(256) void prep1_kernel(const float* __restrict__ x,
                                                    const float* __restrict__ W,
                                                    unsigned short* __restrict__ xb,
                                                    float* __restrict__ rnw,
                                                    int N, int nxb) {
  const int bid = blockIdx.x;
  if (bid < nxb) {
    const int lane = threadIdx.x & 63;
    const int wave = threadIdx.x >> 6;
    const int row  = bid * 4 + wave;
    const float4* xr = (const float4*)(x + (size_t)row * 512);
    const float4 v0 = xr[lane * 2];
    const float4 v1 = xr[lane * 2 + 1];
    float s = v0.x*v0.x + v0.y*v0.y + v0.z*v0.z + v0.w*v0.w
            + v1.x*v1.x + v1.y*v1.y + v1.z*v1.z + v1.w*v1.w;
#pragma unroll
    for (int off = 32; off > 0; off >>= 1) s += __shfl_xor(s, off);
    const float r = rsqrtf(fmaxf(s, L2EPS));
    short8 o;
    o[0] = (short)f2bf(v0.x * r); o[1] = (short)f2bf(v0.y * r);
    o[2] = (short)f2bf(v0.z * r); o[3] = (short)f2bf(v0.w * r);
    o[4] = (short)f2bf(v1.x * r); o[5] = (short)f2bf(v1.y * r);
    o[6] = (short)f2bf(v1.z * r); o[7] = (short)f2bf(v1.w * r);
    *(short8*)(xb + (size_t)row * 512 + lane * 8) = o;
  } else {
    const int d = bid - nxb;
    const float2* row2 = (const float2*)(W + (size_t)d * N);
    const int n2 = N >> 1;
    float s = 0.f;
    for (int i = threadIdx.x; i < n2; i += 256) {
      const float2 v = row2[i];
      s += v.x * v.x + v.y * v.y;
    }
    if (threadIdx.x == 0 && (N & 1)) {
      const float v = W[(size_t)d * N + (N - 1)];
      s += v * v;
    }
#pragma unroll
    for (int off = 32; off > 0; off >>= 1) s += __shfl_xor(s, off);
    __shared__ float red[4];
    if ((threadIdx.x & 63) == 0) red[threadIdx.x >> 6] = s;
    __syncthreads();
    if (threadIdx.x == 0)
      rnw[d] = rsqrtf(fmaxf(red[0] + red[1] + red[2] + red[3], L2EPS));
  }
}

// ---------------------------------------------------------------------------
// Kernel 2: BT[n][d] = bf16(W[d][n] * rnw[d]), n in [0, Npad) zero-padded.
// W is L3-warm from kernel 1's wnorm pass.
// ---------------------------------------------------------------------------
__global__ __launch_bounds__(256) void wtrans_kernel(const float* __restrict__ W,
                                                     const float* __restrict__ rnw,
                                                     unsigned short* __restrict__ BT,
                                                     int N, int nwx) {
  __shared__ unsigned short tile[32][33];
  const int n0 = (blockIdx.x % nwx) * 32;
  const int d0 = (blockIdx.x / nwx) * 32;
  const int tx = threadIdx.x & 31;
  const int ty = threadIdx.x >> 5;  // 0..7
#pragma unroll
  for (int i = 0; i < 4; ++i) {
    const int dl = ty + i * 8;
    const int d = d0 + dl;
    const int n = n0 + tx;
    float v = 0.f;
    if (n < N) v = W[(size_t)d * N + n] * rnw[d];
    tile[tx][dl] = f2bf(v);
  }
  __syncthreads();
#pragma unroll
  for (int i = 0; i < 4; ++i) {
    const int nl = ty + i * 8;
    BT[(size_t)(n0 + nl) * 512 + d0 + tx] = tile[nl][tx];
  }
}

// ---------------------------------------------------------------------------
// Kernel 3: GEMM = r8 skeleton (128x128, 4 waves, BK=64, single LDS buffer,
// compiler-owned schedule, chunk-XOR swizzle both sides) with:
//  - 2D XCD rectangles: grid padded to 48x32=1536, XCD c owns a 16by x 12bx
//    rect (A 2MB + B 1.5MB fits one XCD L2) -> lower FETCH.
//  - 5 blocks/CU (__launch_bounds__(256,5); 5 x 32KB = 160KB LDS exactly).
// ---------------------------------------------------------------------------
__global__ __launch_bounds__(256, 5) void gemm_kernel(
    const unsigned short* __restrict__ A,   // (4096,512) bf16 (x-normalized)
    const unsigned short* __restrict__ BT,  // (6144,512) bf16 (W^T * rnw, padded)
    float* __restrict__ C,                  // (4096,N) f32
    int N) {
  __shared__ unsigned short As[128 * 64];
  __shared__ unsigned short Bs[128 * 64];

  const int tid = threadIdx.x;
  const int l   = tid & 63;
  const int w   = tid >> 6;   // 0..3
  const int wr  = w >> 1;     // 0..1
  const int wc  = w & 1;      // 0..1

  // 2D XCD rect swizzle: 1536 blocks = 8 rects x 192 (16by x 12bx).
  const int bid = blockIdx.x;
  const int c   = bid & 7;          // XCD (dispatch round-robins bid%8)
  const int i   = bid >> 3;         // 0..191 within rect
  const int by  = (c >> 2) * 16 + i / 12;    // 0..31
  const int bx  = (c & 3) * 12 + i % 12;     // 0..47 (bx=47 cols are dummies)
  const int row0 = by * 128;
  const int col0 = bx * 128;

  floatx4 acc[4][4];
#pragma unroll
  for (int m = 0; m < 4; ++m)
#pragma unroll
    for (int n = 0; n < 4; ++n)
      acc[m][n] = (floatx4){0.f, 0.f, 0.f, 0.f};

  // staging: one instr = 256 thr x 16B = 4KB = 32 rows of 128B; 4 per matrix.
  // LDS dest linear (tid*16B); SOURCE chunk pre-swizzled (rule #21):
  // chunk_g = (tid&7) ^ (row&7), row&7 = (tid>>3)&7 (rows step by 32).
  const int srow = tid >> 3;                               // 0..31
  const int sch  = ((tid & 7) ^ (srow & 7)) * 8;           // elems
  const unsigned short* Ap = A  + (size_t)(row0 + srow) * 512 + sch;
  const unsigned short* Bp = BT + (size_t)(col0 + srow) * 512 + sch;
  const int lo = tid * 8;                                  // LDS elems

  // frag-read geometry: elem = row*64 + ((ks*4+q4)^(row&7))*8; consecutive
  // 8-lane groups cover 8 distinct 16B bank-groups (0 conflicts, r3-measured).
  const int ln15 = l & 15;
  const int q4   = l >> 4;
  const int e7   = ln15 & 7;
  const int cs0  = ((q4) ^ e7) * 8;
  const int cs1  = ((4 + q4) ^ e7) * 8;
  const int aoff = (wr * 64 + ln15) * 64;   // + m*1024
  const int boff = (wc * 64 + ln15) * 64;   // + n*1024

  for (int t = 0; t < 8; ++t) {
#pragma unroll
    for (int i2 = 0; i2 < 4; ++i2)
      gload_lds16(Ap + (size_t)(i2 * 32) * 512 + t * 64, &As[i2 * 2048 + lo]);
#pragma unroll
    for (int i2 = 0; i2 < 4; ++i2)
      gload_lds16(Bp + (size_t)(i2 * 32) * 512 + t * 64, &Bs[i2 * 2048 + lo]);
    __syncthreads();
#pragma unroll
    for (int ks = 0; ks < 2; ++ks) {
      const int cs = ks ? cs1 : cs0;
      short8 af[4], bf[4];
#pragma unroll
      for (int m = 0; m < 4; ++m) af[m] = *(const short8*)&As[aoff + m * 1024 + cs];
#pragma unroll
      for (int n = 0; n < 4; ++n) bf[n] = *(const short8*)&Bs[boff + n * 1024 + cs];
#pragma unroll
      for (int m = 0; m < 4; ++m)
#pragma unroll
        for (int n = 0; n < 4; ++n)
          acc[m][n] = __builtin_amdgcn_mfma_f32_16x16x32_bf16(af[m], bf[n], acc[m][n], 0, 0, 0);
    }
    __syncthreads();
  }

  // epilogue: C/D layout col=lane&15, row=(lane>>4)*4+r; n-inner; plain
  // stores through L2 (measured near-ideal WRITE 103MB).
  const int rb = row0 + wr * 64 + q4 * 4;
  const int cb = col0 + wc * 64 + ln15;
#pragma unroll
  for (int m = 0; m < 4; ++m) {
#pragma unroll
    for (int r = 0; r < 4; ++r) {
      const size_t o = (size_t)(rb + m * 16 + r) * N + cb;
#pragma unroll
      for (int n = 0; n < 4; ++n) {
        if (cb + n * 16 < N) C[o + n * 16] = acc[m][n][r];
      }
    }
  }
}

// ---------------------------------------------------------------------------
extern "C" void kernel_launch(void* const* d_in, const int* in_sizes, int n_in,
                              void* d_out, int out_size, void* d_ws, size_t ws_size,
                              hipStream_t stream) {
  const float* x = (const float*)d_in[0];
  const float* W = (const float*)d_in[1];
  float* out = (float*)d_out;

  const int D = 512;
  const int B = in_sizes[0] / D;            // 4096
  const int N = in_sizes[1] / D;            // 5994
  const int Npad = 6144;                    // 48 x 128 (covers dummy bx=47)

  char* ws = (char*)d_ws;
  unsigned short* xb  = (unsigned short*)ws;                          // B*D*2
  unsigned short* BTb = (unsigned short*)(ws + (size_t)B * D * 2);    // Npad*D*2
  float* rnw = (float*)(ws + (size_t)B * D * 2 + (size_t)Npad * D * 2);

  const int nxb = B / 4;           // 1024 xnorm blocks
  const int nwx = Npad / 32;       // 192 wtrans tiles per d-stripe

  prep1_kernel<<<nxb + D, 256, 0, stream>>>(x, W, xb, rnw, N, nxb);
  wtrans_kernel<<<nwx * (D / 32), 256, 0, stream>>>(W, rnw, BTb, N, nwx);
  gemm_kernel<<<1536, 256, 0, stream>>>(xb, BTb, out, N);
}